// Round 9
// baseline (573.543 us; speedup 1.0000x reference)
//
#include <hip/hip_runtime.h>

// SingleLSTM: B=32768, T=28, INPUT=28, HIDDEN=128, LABELS=10, fp32.
// R21: producer/consumer wave specialization. R13-R20 invariance
// (Mfma ~31, VALU ~55, 214-253us across ping-pong/SGB/setprio/
// frag-pipe/indep-barrier) is explained by: (a) MFMA blocks its own
// wave -> intra-wave MFMA||VALU overlap impossible; (b) in-phase is a
// STABLE equilibrium for symmetric waves (contention slows both
// equally), so cross-wave overlap (m114) never engages. Fix: make the
// phase split STRUCTURAL. 8 waves: waves 0-3 = producers (one/SIMD,
// MFMA only), waves 4-7 = consumers (act only). Producer p computes
// all 4 gates for h-cols [32p,32p+32): 8 col-tiles x 8 row-tiles x
// 5 MFMA = 320/step, weights in 160 VGPR, ax/ah frags read ONCE per
// row-tile (5 ds_read_b128, amortized over 8 col-tiles - 8x fewer
// frag reads than R13). Gates written f32 col-major to gbuf
// ([ct][col][row] -> dense 512B b128 writes, conflict-free), double-
// buffered by rt&1. Consumer p (same SIMD) spins on flg[p][rt]==t+1,
// reads 8x f32x4, acts 8 cells/lane (creg[64]), writes h, acks.
// Producer waits ack >= t*8+rt-1 for rt>=2 (step barrier covers rt<2).
// Monotone flags -> no reset. One __syncthreads per step per wave
// (counts match across divergent roles). Ledger: producer 6.2k cy
// MFMA-pipe + gaps; consumer ~10k cy trans/VALU -> step ~10.5k vs
// 18.4k serialized now.
// Kept (verified): bias folded into GEMM (x k=28,29 slots=1.0, Wx frag
// carries hi/lo two-f16 bias split on quad==3, acc init=ZERO), linear
// x staging over all 512 threads (R17), fp16 datapath, W/bias
// pre-scaled {-L2E, 2L2E, -L2E, -L2E}, c in 2*L2E units, h dbuf,
// HSTRIDE=136. LDS 151.7KB -> 1 block/CU.

typedef _Float16 f16x8 __attribute__((ext_vector_type(8)));
typedef float f32x4 __attribute__((ext_vector_type(4)));

#define HSTRIDE 136    // f16 elems; 272B row = 17*16B (b128-aligned rows)
#define L2E 1.44269504f

__global__ __launch_bounds__(512, 2)
void lstm_r21(const float* __restrict__ x,      // [B][28][28]
              const float* __restrict__ W,      // [156][512]
              const float* __restrict__ b,      // [512]
              const float* __restrict__ Wfc,    // [128][10]
              const float* __restrict__ bfc,    // [10]
              float* __restrict__ out)          // [B][10]
{
    __shared__ __align__(16) _Float16 h_s[2][128 * HSTRIDE];  // 69632 B
    __shared__ __align__(16) _Float16 xs[2][8 * 512];         // 16384 B
    __shared__ __align__(16) float gbuf[4][2][8][16][16];     // 65536 B
    __shared__ int flg[4][8];                                 //   128 B
    __shared__ int ack[4];                                    //    16 B
    // total 151696 B -> one block per CU

    const int tid  = threadIdx.x;
    const int wave = tid >> 6;
    const int lane = tid & 63;
    const int m16  = lane & 15;
    const int quad = lane >> 4;
    const int rbase = blockIdx.x * 128;
    const bool producer = (wave < 4);
    const int p = wave & 3;             // pair index

    // ---- init: zero h buf0; xs bias slots; flags ----
    for (int i = tid; i < 128 * HSTRIDE; i += 512) h_s[0][i] = (_Float16)0.0f;
    for (int i = tid; i < 2 * 8 * 512; i += 512) {
        const int q = i & 511;
        const bool bslot = ((q >> 7) == 3) && (((q & 7) == 4) || ((q & 7) == 5));
        ((_Float16*)xs)[i] = bslot ? (_Float16)1.0f : (_Float16)0.0f;
    }
    if (tid < 32) ((int*)flg)[tid] = 0;
    if (tid < 4)  ack[tid] = 0;

    // ---- producer weights: 8 col-tiles (4 gates x 2 halves), K=160 ----
    // Wt[ct][0] = Wx frag (K 0..31, bias in k=28/29), Wt[ct][1..4] = Wh.
    f16x8 Wt[8][5];
    if (producer) {
        #pragma unroll
        for (int ct = 0; ct < 8; ct++) {
            const int g = ct >> 1, half = ct & 1;
            const int col = g * 128 + p * 32 + half * 16 + m16;
            const float sc = (g == 1) ? 2.0f * L2E : -L2E;
            f16x8 w8;
            #pragma unroll
            for (int j = 0; j < 8; j++) {
                const int kk = quad * 8 + j;
                w8[j] = (kk < 28) ? (_Float16)(sc * W[kk * 512 + col]) : (_Float16)0.0f;
            }
            if (quad == 3) {
                const float bv = sc * (b[col] + (g == 2 ? 1.0f : 0.0f));
                const _Float16 hi = (_Float16)bv;
                w8[4] = hi;
                w8[5] = (_Float16)(bv - (float)hi);
            }
            Wt[ct][0] = w8;
            #pragma unroll
            for (int ks = 0; ks < 4; ks++) {
                f16x8 h8;
                #pragma unroll
                for (int j = 0; j < 8; j++)
                    h8[j] = (_Float16)(sc * W[(28 + ks * 32 + quad * 8 + j) * 512 + col]);
                Wt[ct][ks + 1] = h8;
            }
        }
    }

    // barrier: zero/bias/flag init complete before t=0 staging
    __syncthreads();

    // ---- x staging, linear form (all 512 threads): slot = e*512+tid ----
    const int row16 = (tid >> 3) & 15;
    const int sk    = ((tid >> 7) & 3) * 8 + (tid & 7);
    const bool valid = (sk < 28);
    const int goff0 = (rbase + row16) * 784 + sk;

    #pragma unroll
    for (int e = 0; e < 8; e++)
        if (valid) xs[0][e * 512 + tid] = (_Float16)x[goff0 + e * 12544];
    __syncthreads();

    const int foff = quad * 128 + m16 * 8;
    const f32x4 ZERO = (f32x4){0.0f, 0.0f, 0.0f, 0.0f};

    float creg[64];   // consumer only: 8 rt x 2 half x 4 r
    #pragma unroll
    for (int i = 0; i < 64; i++) creg[i] = 0.0f;

    int buf = 0;
    for (int t = 0; t < 28; t++) {
        const int nb = buf ^ 1;

        // EARLY: issue global loads for t+1 (all threads)
        float xv[8];
        if (t < 27 && valid) {
            const float* xt = x + (t + 1) * 28;
            #pragma unroll
            for (int e = 0; e < 8; e++) xv[e] = xt[goff0 + e * 12544];
        }

        if (producer) {
            // ================= PRODUCER: MFMA only =================
            for (int rt = 0; rt < 8; rt++) {
                // wait for consumer to release gbuf[rt&1] (rt-2 consumed);
                // step barrier already guarantees rt<2 slots are free
                if (rt >= 2) {
                    const int need = t * 8 + rt - 1;
                    while (*(volatile int*)&ack[p] < need)
                        __builtin_amdgcn_s_sleep(1);
                }
                // fragments once per row-tile, shared by 8 col-tiles
                f16x8 ax = *(const f16x8*)(&xs[buf][rt * 512 + foff]);
                f16x8 ah0 = *(const f16x8*)(&h_s[buf][(rt * 16 + m16) * HSTRIDE + 0 * 32 + quad * 8]);
                f16x8 ah1 = *(const f16x8*)(&h_s[buf][(rt * 16 + m16) * HSTRIDE + 1 * 32 + quad * 8]);
                f16x8 ah2 = *(const f16x8*)(&h_s[buf][(rt * 16 + m16) * HSTRIDE + 2 * 32 + quad * 8]);
                f16x8 ah3 = *(const f16x8*)(&h_s[buf][(rt * 16 + m16) * HSTRIDE + 3 * 32 + quad * 8]);
                #pragma unroll
                for (int ct = 0; ct < 8; ct++) {
                    f32x4 acc = __builtin_amdgcn_mfma_f32_16x16x32_f16(ax,  Wt[ct][0], ZERO, 0, 0, 0);
                    acc = __builtin_amdgcn_mfma_f32_16x16x32_f16(ah0, Wt[ct][1], acc, 0, 0, 0);
                    acc = __builtin_amdgcn_mfma_f32_16x16x32_f16(ah1, Wt[ct][2], acc, 0, 0, 0);
                    acc = __builtin_amdgcn_mfma_f32_16x16x32_f16(ah2, Wt[ct][3], acc, 0, 0, 0);
                    acc = __builtin_amdgcn_mfma_f32_16x16x32_f16(ah3, Wt[ct][4], acc, 0, 0, 0);
                    // gates f32, col-major: lane (m16,quad) -> rows quad*4..+3
                    *(f32x4*)&gbuf[p][rt & 1][ct][m16][quad * 4] = acc;
                }
                // publish: gate writes drained, then flag
                asm volatile("s_waitcnt lgkmcnt(0)" ::: "memory");
                if (lane == 0) *(volatile int*)&flg[p][rt] = t + 1;
            }
        } else {
            // ================= CONSUMER: act only =================
            for (int rt = 0; rt < 8; rt++) {
                // wait for producer's gates(rt)
                while (*(volatile int*)&flg[p][rt] < t + 1) { }
                f32x4 gv[4][2];
                #pragma unroll
                for (int g = 0; g < 4; g++)
                    #pragma unroll
                    for (int half = 0; half < 2; half++)
                        gv[g][half] = *(const f32x4*)&gbuf[p][rt & 1][g * 2 + half][m16][quad * 4];
                // release gbuf[rt&1] for producer's rt+2
                asm volatile("s_waitcnt lgkmcnt(0)" ::: "memory");
                if (lane == 0) *(volatile int*)&ack[p] = t * 8 + rt + 1;

                #pragma unroll
                for (int half = 0; half < 2; half++)
                    #pragma unroll
                    for (int r = 0; r < 4; r++) {
                        float ei  = __builtin_amdgcn_exp2f(gv[0][half][r]);   // e^-i
                        float e2j = __builtin_amdgcn_exp2f(gv[1][half][r]);   // e^2j
                        float ef  = __builtin_amdgcn_exp2f(gv[2][half][r]);   // e^-(f+1)
                        float eo  = __builtin_amdgcn_exp2f(gv[3][half][r]);   // e^-o
                        float A   = 1.0f + ei;
                        float Bv  = e2j + 1.0f;
                        float C   = 1.0f + ef;
                        float AB  = A * Bv;
                        float rP  = __builtin_amdgcn_rcpf(AB * C);
                        float num = __builtin_fmaf(e2j, 2.0f * L2E, -2.0f * L2E);
                        const int ci = rt * 8 + half * 4 + r;
                        float cn  = __builtin_fmaf(creg[ci], AB * rP, num * (C * rP));
                        creg[ci] = cn;
                        float e2c = __builtin_amdgcn_exp2f(cn);               // e^2c
                        float rQ  = __builtin_amdgcn_rcpf((e2c + 1.0f) * (1.0f + eo));
                        float hv  = (e2c - 1.0f) * rQ;
                        h_s[nb][(rt * 16 + quad * 4 + r) * HSTRIDE + p * 32 + half * 16 + m16] = (_Float16)hv;
                    }
            }
        }

        // LATE: stage x(t+1) (all threads)
        if (t < 27 && valid) {
            #pragma unroll
            for (int e = 0; e < 8; e++)
                xs[nb][e * 512 + tid] = (_Float16)xv[e];
        }
        __syncthreads();   // one barrier per step per wave, both roles
        buf = nb;
    }

    // ---- FC epilogue: logits = h @ Wfc + bfc (1280 outputs) ----
    for (int i = tid; i < 1280; i += 512) {
        const int row = i / 10, lab = i % 10;
        float acc = bfc[lab];
        #pragma unroll 8
        for (int k = 0; k < 128; k++)
            acc += (float)h_s[buf][row * HSTRIDE + k] * Wfc[k * 10 + lab];
        out[(size_t)(rbase + row) * 10 + lab] = acc;
    }
}

extern "C" void kernel_launch(void* const* d_in, const int* in_sizes, int n_in,
                              void* d_out, int out_size, void* d_ws, size_t ws_size,
                              hipStream_t stream) {
    const float* x   = (const float*)d_in[0];
    const float* W   = (const float*)d_in[1];
    const float* b   = (const float*)d_in[2];
    const float* Wfc = (const float*)d_in[3];
    const float* bfc = (const float*)d_in[4];
    float* out = (float*)d_out;

    const int B = in_sizes[0] / (28 * 28);   // 32768
    const int blocks = B / 128;              // 256 = one per CU
    lstm_r21<<<blocks, 512, 0, stream>>>(x, W, b, Wfc, bfc, out);
}